// Round 12
// baseline (31.352 us; speedup 1.0000x reference)
//
#include <hip/hip_runtime.h>
#include <math.h>

// LightweightConv1dTBC: out[t,b,c] = sum_k x[t-15+k, b, c] * softmax(w[h(c),:])[k] + bias[c]
// T=2048 B=8 C=1024 H=16 K=31 P=15, R = C/H = 64 channels per head.
//
// R11 = R3 per-thread structure (best: 28.8us; scalar coalesced loads,
// 16-deep acc strip, SGPR weights, NT stores, no occupancy hints) with the
// work->block->XCD mapping changed:
//  - 1024-thread block = all channels of one (b, t-strip): wave w == head w
//    (weights stay wave-uniform), each t-row store is a 4KB contiguous
//    cluster (was 1KB), loads march linearly in t.
//  - 1-D grid, b = bid&7, z = bid>>3: round-robin dispatch puts all blocks
//    of batch b on XCD b with z ascending -> 120KB z-neighbor halo stays in
//    that XCD's L2.
//  - boundary check is block-uniform (z==0 || z==127).

#define T_DIM 2048
#define B_DIM 8
#define C_DIM 1024
#define H_DIM 16
#define K_DIM 31
#define P_PAD 15
#define STRIP 16
#define NZ (T_DIM / STRIP)          // 128
#define NWG (B_DIM * NZ)            // 1024 blocks

template<bool CHECK>
__device__ __forceinline__ void run_strip(const float* __restrict__ xb,
                                          float* __restrict__ ob,
                                          const float (&w)[K_DIM],
                                          float bv, int t0)
{
    float acc[STRIP];
    #pragma unroll
    for (int i = 0; i < STRIP; ++i) acc[i] = bv;

    #pragma unroll
    for (int r = 0; r < STRIP + K_DIM - 1; ++r) {   // 46 streamed inputs
        const int t = t0 - P_PAD + r;
        float xv = 0.f;
        if (!CHECK || ((unsigned)t < (unsigned)T_DIM)) {
            xv = xb[(size_t)t * (B_DIM * C_DIM)];
        }
        #pragma unroll
        for (int i = 0; i < STRIP; ++i) {
            const int k = r - i;
            if (k >= 0 && k < K_DIM) {              // folds statically
                acc[i] = fmaf(xv, w[k], acc[i]);
            }
        }
    }

    #pragma unroll
    for (int i = 0; i < STRIP; ++i) {
        __builtin_nontemporal_store(acc[i], &ob[(size_t)(t0 + i) * (B_DIM * C_DIM)]);
    }
}

__global__ __launch_bounds__(1024)
void lwconv_tbc_kernel(
    const float* __restrict__ x,       // (T, B, C)
    const float* __restrict__ weight,  // (H, 1, K)
    const float* __restrict__ bias,    // (C,)
    float* __restrict__ out)           // (T, B, C)
{
    const int tid  = threadIdx.x;
    const int lane = tid & 63;
    const int c    = tid;              // block covers all 1024 channels
    const int h    = tid >> 6;         // wave w == head w (wave-uniform)

    const int bid = blockIdx.x;
    const int b   = bid & 7;           // round-robin -> XCD b gets batch b
    const int z   = bid >> 3;          // z ascending within each XCD
    const int t0  = z * STRIP;

    // --- wave-level softmax of this head's 31 weights ---
    float wv = -1e30f;
    if (lane < K_DIM) wv = weight[h * K_DIM + lane];
    float m = wv;
    #pragma unroll
    for (int off = 32; off; off >>= 1) m = fmaxf(m, __shfl_xor(m, off));
    float e = (lane < K_DIM) ? expf(wv - m) : 0.f;
    float s = e;
    #pragma unroll
    for (int off = 32; off; off >>= 1) s += __shfl_xor(s, off);
    const float p = e / s;

    // broadcast to SGPRs (wave-uniform weights, 0 VGPR cost)
    float w[K_DIM];
    #pragma unroll
    for (int k = 0; k < K_DIM; ++k) {
        union { float f; int i; } u;
        u.f = p;
        u.i = __builtin_amdgcn_readlane(u.i, k);
        w[k] = u.f;
    }

    const float bv = bias[c];
    const float* xb = x + (size_t)b * C_DIM + c;
    float* ob = out + (size_t)b * C_DIM + c;

    // interior strips need rows t0-15 .. t0+STRIP-1+15 all in [0, T)
    if (z == 0 || z == NZ - 1) run_strip<true >(xb, ob, w, bv, t0);
    else                       run_strip<false>(xb, ob, w, bv, t0);
}

extern "C" void kernel_launch(void* const* d_in, const int* in_sizes, int n_in,
                              void* d_out, int out_size, void* d_ws, size_t ws_size,
                              hipStream_t stream) {
    const float* x      = (const float*)d_in[0];
    const float* weight = (const float*)d_in[1];
    const float* bias   = (const float*)d_in[2];
    float* out = (float*)d_out;

    lwconv_tbc_kernel<<<dim3(NWG), dim3(1024), 0, stream>>>(x, weight, bias, out);
}